// Round 4
// baseline (569.897 us; speedup 1.0000x reference)
//
#include <hip/hip_runtime.h>
#include <math.h>

#define INPUT_DIM 561
#define NCD 32   // NUM_CAPS * CAP_DIM

// ---------------------------------------------------------------------------
// Prep: Wt[k][c] = cap_W[c][k] * fw[k]   (fold feature_weights into weights;
// [561][32] layout so per-k rows are contiguous -> batched scalar loads)
// ---------------------------------------------------------------------------
__global__ void prep_wt(const float* __restrict__ capW,
                        const float* __restrict__ fw,
                        float* __restrict__ Wt) {
    int idx = blockIdx.x * blockDim.x + threadIdx.x;
    if (idx < INPUT_DIM * NCD) {
        int k = idx >> 5;       // 0..560
        int c = idx & 31;       // 0..31
        Wt[idx] = capW[c * INPUT_DIM + k] * fw[k];
    }
}

// ---------------------------------------------------------------------------
// Async global->LDS staging: one instruction per row p; 64 lanes x 4B land in
// the contiguous 256B row dst[p][0..63] (wave-uniform LDS base + lane*4 —
// the m104/m108 constraint). Row-pad (65) sits BETWEEN rows, so each
// instruction's destination window stays contiguous (m173).
// ---------------------------------------------------------------------------
__device__ __forceinline__ void issue_rows(const float* __restrict__ X,
                                           int r0, int k0,
                                           float (*dst)[65],
                                           int pbeg, int t) {
    int kk = k0 + t;
    if (kk > INPUT_DIM - 1) kk = INPUT_DIM - 1;   // clamp: no OOB on tail cols
    #pragma unroll
    for (int p = pbeg; p < pbeg + 32; ++p) {
        const float* g = X + (size_t)(r0 + p) * INPUT_DIM + kk;
        __builtin_amdgcn_global_load_lds(
            (const __attribute__((address_space(1))) void*)g,
            (__attribute__((address_space(3))) void*)&dst[p][0],
            4, 0, 0);
    }
}

__device__ __forceinline__ void gemm_cols(const float* __restrict__ Wt,
                                          const float (*xt)[65], int t,
                                          int k0, int kbeg, int kend,
                                          float* __restrict__ acc,
                                          int use_wt,
                                          const float* __restrict__ capW,
                                          const float* __restrict__ fw) {
    if (use_wt) {
        #pragma unroll 4
        for (int k = kbeg; k < kend; ++k) {
            const float xv = xt[t][k];                       // 2-way LDS = free
            const float* __restrict__ wrow = Wt + (k0 + k) * NCD;  // uniform -> s_load
            #pragma unroll
            for (int c = 0; c < NCD; ++c)
                acc[c] = fmaf(xv, wrow[c], acc[c]);
        }
    } else {
        #pragma unroll 2
        for (int k = kbeg; k < kend; ++k) {
            const float xv = xt[t][k] * fw[k0 + k];
            #pragma unroll
            for (int c = 0; c < NCD; ++c)
                acc[c] = fmaf(xv, capW[c * INPUT_DIM + k0 + k], acc[c]);
        }
    }
}

// ---------------------------------------------------------------------------
// Main fused kernel: 1 thread per row, 64-thread (1-wave) blocks.
// Phase 1: caps = (x*fw) @ cap_W.T + cap_b  (async-DMA LDS tiles, s_load W)
// Phase 2: attention + MLP head, fully register-resident, static indexing.
// ---------------------------------------------------------------------------
__global__ __launch_bounds__(64) void harcnet_main(
    const float* __restrict__ X,
    const float* __restrict__ fw,
    const float* __restrict__ capW, const float* __restrict__ cap_b,
    const float* __restrict__ qW, const float* __restrict__ qb,
    const float* __restrict__ kW, const float* __restrict__ kb,
    const float* __restrict__ vW, const float* __restrict__ vb,
    const float* __restrict__ fc1W, const float* __restrict__ fc1b,
    const float* __restrict__ fc2W, const float* __restrict__ fc2b,
    const float* __restrict__ resW, const float* __restrict__ resb,
    const float* __restrict__ outW, const float* __restrict__ outb,
    const float* __restrict__ Wt, int use_wt,
    float* __restrict__ out)
{
    __shared__ float xt[2][64][65];   // double-buffered X tile; read bank =
                                      // (t+k)%32 -> 2-way = free (m136)
    const int t  = threadIdx.x;       // 0..63 ; owns row r0+t
    const int r0 = blockIdx.x * 64;

    float acc[NCD];
    #pragma unroll
    for (int c = 0; c < NCD; ++c) acc[c] = cap_b[c];   // uniform -> s_load

    // prologue: DMA chunk 0 into buf 0
    issue_rows(X, r0, 0, xt[0], 0, t);
    issue_rows(X, r0, 0, xt[0], 32, t);

    int cur = 0;
    for (int ch = 0; ch < 9; ++ch) {
        // Explicit DMA drain: do NOT rely on single-wave __syncthreads
        // codegen keeping the vmcnt(0) (1-wave workgroup, barrier may elide).
        asm volatile("s_waitcnt vmcnt(0)" ::: "memory");
        __syncthreads();

        const int k0   = ch * 64;
        const int kend = (ch == 8) ? (INPUT_DIM - 512) : 64;   // 49 on last
        const int kmid = (kend < 32) ? kend : 32;

        // interleave next-chunk DMA issue with compute
        if (ch < 8) issue_rows(X, r0, k0 + 64, xt[cur ^ 1], 0, t);
        gemm_cols(Wt, xt[cur], t, k0, 0, kmid, acc, use_wt, capW, fw);
        if (ch < 8) issue_rows(X, r0, k0 + 64, xt[cur ^ 1], 32, t);
        gemm_cols(Wt, xt[cur], t, k0, kmid, kend, acc, use_wt, capW, fw);

        cur ^= 1;
    }

    // ---------------- Phase 2: per-row head (all registers) ----------------
    // caps[q][e] == acc[q*8+e]; all weight reads wave-uniform -> scalar pipe
    float Km[32], Vm[32];
    #pragma unroll
    for (int q = 0; q < 4; ++q) {
        #pragma unroll
        for (int d = 0; d < 8; ++d) {
            float ka = kb[d], va = vb[d];
            #pragma unroll
            for (int e = 0; e < 8; ++e) {
                ka = fmaf(acc[q * 8 + e], kW[d * 8 + e], ka);
                va = fmaf(acc[q * 8 + e], vW[d * 8 + e], va);
            }
            Km[q * 8 + d] = ka;
            Vm[q * 8 + d] = va;
        }
    }

    float flat[32];
    const float rs8 = 0.35355339059327373f;  // 1/sqrt(8)
    #pragma unroll
    for (int q = 0; q < 4; ++q) {
        float Q[8];
        #pragma unroll
        for (int d = 0; d < 8; ++d) {
            float a = qb[d];
            #pragma unroll
            for (int e = 0; e < 8; ++e)
                a = fmaf(acc[q * 8 + e], qW[d * 8 + e], a);
            Q[d] = a;
        }
        float sc[4];
        #pragma unroll
        for (int kq = 0; kq < 4; ++kq) {
            float a = 0.0f;
            #pragma unroll
            for (int d = 0; d < 8; ++d)
                a = fmaf(Q[d], Km[kq * 8 + d], a);
            sc[kq] = a * rs8;
        }
        const float m  = fmaxf(fmaxf(sc[0], sc[1]), fmaxf(sc[2], sc[3]));
        const float e0 = __expf(sc[0] - m);
        const float e1 = __expf(sc[1] - m);
        const float e2 = __expf(sc[2] - m);
        const float e3 = __expf(sc[3] - m);
        const float inv = 1.0f / (e0 + e1 + e2 + e3);
        #pragma unroll
        for (int d = 0; d < 8; ++d)
            flat[q * 8 + d] =
                (e0 * Vm[0 * 8 + d] + e1 * Vm[1 * 8 + d] +
                 e2 * Vm[2 * 8 + d] + e3 * Vm[3 * 8 + d]) * inv;
    }

    // fc1 (fully unrolled: res[] statically indexed -> stays in VGPRs)
    float res[64];
    #pragma unroll
    for (int j = 0; j < 64; ++j) {
        float a = fc1b[j];
        #pragma unroll
        for (int i = 0; i < 32; ++i)
            a = fmaf(flat[i], fc1W[j * 32 + i], a);
        res[j] = fmaxf(a, 0.0f);
    }

    // fc2 + residual + relu + out-proj, one hidden unit at a time
    float o[6];
    #pragma unroll
    for (int p = 0; p < 6; ++p) o[p] = outb[p];

    for (int c = 0; c < 64; ++c) {
        float a = fc2b[c] + resb[c];
        #pragma unroll
        for (int j = 0; j < 64; ++j)
            a = fmaf(res[j], fc2W[c * 64 + j], a);
        #pragma unroll
        for (int i = 0; i < 32; ++i)
            a = fmaf(flat[i], resW[c * 32 + i], a);
        a = fmaxf(a, 0.0f);
        #pragma unroll
        for (int p = 0; p < 6; ++p)
            o[p] = fmaf(a, outW[p * 64 + c], o[p]);
    }

    const int row = r0 + t;
    #pragma unroll
    for (int p = 0; p < 6; ++p)
        out[row * 6 + p] = o[p];
}

// ---------------------------------------------------------------------------
extern "C" void kernel_launch(void* const* d_in, const int* in_sizes, int n_in,
                              void* d_out, int out_size, void* d_ws, size_t ws_size,
                              hipStream_t stream) {
    const float* X     = (const float*)d_in[0];
    const float* fw    = (const float*)d_in[1];
    const float* capW  = (const float*)d_in[2];
    const float* cap_b = (const float*)d_in[3];
    const float* qW    = (const float*)d_in[4];
    const float* qb    = (const float*)d_in[5];
    const float* kW    = (const float*)d_in[6];
    const float* kb    = (const float*)d_in[7];
    const float* vW    = (const float*)d_in[8];
    const float* vb    = (const float*)d_in[9];
    const float* fc1W  = (const float*)d_in[10];
    const float* fc1b  = (const float*)d_in[11];
    const float* fc2W  = (const float*)d_in[12];
    const float* fc2b  = (const float*)d_in[13];
    const float* resW  = (const float*)d_in[14];
    const float* resb  = (const float*)d_in[15];
    const float* outW  = (const float*)d_in[16];
    const float* outb  = (const float*)d_in[17];
    float* out = (float*)d_out;
    float* Wt  = (float*)d_ws;

    const int use_wt =
        (ws_size >= (size_t)(INPUT_DIM * NCD) * sizeof(float)) ? 1 : 0;
    if (use_wt) {
        prep_wt<<<(INPUT_DIM * NCD + 255) / 256, 256, 0, stream>>>(capW, fw, Wt);
    }

    const int nrows = in_sizes[0] / INPUT_DIM;   // 65536
    harcnet_main<<<nrows / 64, 64, 0, stream>>>(
        X, fw, capW, cap_b, qW, qb, kW, kb, vW, vb,
        fc1W, fc1b, fc2W, fc2b, resW, resb, outW, outb,
        Wt, use_wt, out);
}

// Round 6
// 496.411 us; speedup vs baseline: 1.1480x; 1.1480x over previous
//
#include <hip/hip_runtime.h>
#include <math.h>

#define INPUT_DIM 561
#define NCD 32   // NUM_CAPS * CAP_DIM

// ---------------------------------------------------------------------------
// Prep: Wt[k][c] = cap_W[c][k] * fw[k]  (fold feature_weights; [561][32]
// layout so per-k weight rows are contiguous -> batched uniform s_loads)
// ---------------------------------------------------------------------------
__global__ void prep_wt(const float* __restrict__ capW,
                        const float* __restrict__ fw,
                        float* __restrict__ Wt) {
    int idx = blockIdx.x * blockDim.x + threadIdx.x;
    if (idx < INPUT_DIM * NCD) {
        int k = idx >> 5;       // 0..560
        int c = idx & 31;       // 0..31
        Wt[idx] = capW[c * INPUT_DIM + k] * fw[k];
    }
}

// ---------------------------------------------------------------------------
// One K-chunk of the caps GEMM for one row. X staged global->VGPR in
// sub-blocks of <=32 (keeps live xr[] at 32 -> ~90 VGPRs total, no spill
// under the 128-VGPR/4-wave cap). Static indexing only (rule #20).
// Weight rows at wave-uniform addresses -> scalar pipe (s_load), zero VALU.
// No LDS ops in this loop: vmcnt (X) and lgkmcnt (weights) stay decoupled.
// ---------------------------------------------------------------------------
template<int NC>
__device__ __forceinline__ void chunk_fma(const float* __restrict__ Xrow,
                                          int k0,
                                          const float* __restrict__ Wt,
                                          float* __restrict__ acc) {
    constexpr int SB = (NC > 32) ? 32 : NC;
    #pragma unroll
    for (int s = 0; s < NC; s += SB) {
        float xr[SB];
        #pragma unroll
        for (int i = 0; i < SB; ++i) xr[i] = Xrow[k0 + s + i];
        #pragma unroll
        for (int k = 0; k < SB; ++k) {
            const float* __restrict__ wrow = Wt + (size_t)(k0 + s + k) * NCD;
            #pragma unroll
            for (int c = 0; c < NCD; ++c)
                acc[c] = fmaf(xr[k], wrow[c], acc[c]);
        }
    }
}

// ---------------------------------------------------------------------------
// Main fused kernel: 256 threads = 4 waves per block; all 4 waves cover the
// SAME 64 rows (thread t of each wave = row r0+t) over disjoint K-ranges
// (4-way K-split -> 4096 waves total, 16/CU -> TLP hides memory latency).
// Partials reduced through padded LDS; wave 0 runs the register head.
// ---------------------------------------------------------------------------
__global__ __launch_bounds__(256, 4) void harcnet_main(
    const float* __restrict__ X,
    const float* __restrict__ fw,
    const float* __restrict__ capW, const float* __restrict__ cap_b,
    const float* __restrict__ qW, const float* __restrict__ qb,
    const float* __restrict__ kW, const float* __restrict__ kb,
    const float* __restrict__ vW, const float* __restrict__ vb,
    const float* __restrict__ fc1W, const float* __restrict__ fc1b,
    const float* __restrict__ fc2W, const float* __restrict__ fc2b,
    const float* __restrict__ resW, const float* __restrict__ resb,
    const float* __restrict__ outW, const float* __restrict__ outb,
    const float* __restrict__ Wt, int use_wt,
    float* __restrict__ out)
{
    __shared__ float part[4][64][33];   // pad 33: bank (t+c)%32 -> 2-way free
    const int t   = threadIdx.x & 63;   // row within block
    const int w   = threadIdx.x >> 6;   // wave id = K-slice id
    const int r0  = blockIdx.x * 64;
    const int row = r0 + t;
    const float* __restrict__ Xrow = X + (size_t)row * INPUT_DIM;

    float acc[NCD];
    #pragma unroll
    for (int c = 0; c < NCD; ++c) acc[c] = 0.0f;

    if (use_wt) {
        // balanced K-split: wave w gets [64w,64w+64) + [256+64w,256+64w+64)
        // + slice of [512,561): 12/12/12/13 -> 140/140/140/141 cols each
        chunk_fma<64>(Xrow, w * 64,       Wt, acc);
        chunk_fma<64>(Xrow, 256 + w * 64, Wt, acc);
        if (w < 3) chunk_fma<12>(Xrow, 512 + 12 * w, Wt, acc);
        else       chunk_fma<13>(Xrow, 548,          Wt, acc);
    } else {
        // slow-but-correct fallback (not expected: ws_size >= 72KB)
        const int kbeg = w * 141;
        const int kend = (kbeg + 141 < INPUT_DIM) ? kbeg + 141 : INPUT_DIM;
        for (int k = kbeg; k < kend; ++k) {
            const float xv = Xrow[k] * fw[k];
            #pragma unroll
            for (int c = 0; c < NCD; ++c)
                acc[c] = fmaf(xv, capW[c * INPUT_DIM + k], acc[c]);
        }
    }

    // cross-wave reduction via LDS
    #pragma unroll
    for (int c = 0; c < NCD; ++c) part[w][t][c] = acc[c];
    __syncthreads();
    if (w != 0) return;                 // free wave slots for next block

    #pragma unroll
    for (int c = 0; c < NCD; ++c)
        acc[c] = cap_b[c] + part[0][t][c] + part[1][t][c]
                          + part[2][t][c] + part[3][t][c];

    // ---------------- head: per-row, all registers, static indexing --------
    float Km[32], Vm[32];
    #pragma unroll
    for (int q = 0; q < 4; ++q) {
        #pragma unroll
        for (int d = 0; d < 8; ++d) {
            float ka = kb[d], va = vb[d];
            #pragma unroll
            for (int e = 0; e < 8; ++e) {
                ka = fmaf(acc[q * 8 + e], kW[d * 8 + e], ka);
                va = fmaf(acc[q * 8 + e], vW[d * 8 + e], va);
            }
            Km[q * 8 + d] = ka;
            Vm[q * 8 + d] = va;
        }
    }

    float flat[32];
    const float rs8 = 0.35355339059327373f;  // 1/sqrt(8)
    #pragma unroll
    for (int q = 0; q < 4; ++q) {
        float Q[8];
        #pragma unroll
        for (int d = 0; d < 8; ++d) {
            float a = qb[d];
            #pragma unroll
            for (int e = 0; e < 8; ++e)
                a = fmaf(acc[q * 8 + e], qW[d * 8 + e], a);
            Q[d] = a;
        }
        float sc[4];
        #pragma unroll
        for (int kq = 0; kq < 4; ++kq) {
            float a = 0.0f;
            #pragma unroll
            for (int d = 0; d < 8; ++d)
                a = fmaf(Q[d], Km[kq * 8 + d], a);
            sc[kq] = a * rs8;
        }
        const float m  = fmaxf(fmaxf(sc[0], sc[1]), fmaxf(sc[2], sc[3]));
        const float e0 = __expf(sc[0] - m);
        const float e1 = __expf(sc[1] - m);
        const float e2 = __expf(sc[2] - m);
        const float e3 = __expf(sc[3] - m);
        const float inv = 1.0f / (e0 + e1 + e2 + e3);
        #pragma unroll
        for (int d = 0; d < 8; ++d)
            flat[q * 8 + d] =
                (e0 * Vm[0 * 8 + d] + e1 * Vm[1 * 8 + d] +
                 e2 * Vm[2 * 8 + d] + e3 * Vm[3 * 8 + d]) * inv;
    }

    float res[64];
    #pragma unroll
    for (int j = 0; j < 64; ++j) {
        float a = fc1b[j];
        #pragma unroll
        for (int i = 0; i < 32; ++i)
            a = fmaf(flat[i], fc1W[j * 32 + i], a);
        res[j] = fmaxf(a, 0.0f);
    }

    float o[6];
    #pragma unroll
    for (int p = 0; p < 6; ++p) o[p] = outb[p];

    for (int c = 0; c < 64; ++c) {
        float a = fc2b[c] + resb[c];
        #pragma unroll
        for (int j = 0; j < 64; ++j)
            a = fmaf(res[j], fc2W[c * 64 + j], a);
        #pragma unroll
        for (int i = 0; i < 32; ++i)
            a = fmaf(flat[i], resW[c * 32 + i], a);
        a = fmaxf(a, 0.0f);
        #pragma unroll
        for (int p = 0; p < 6; ++p)
            o[p] = fmaf(a, outW[p * 64 + c], o[p]);
    }

    #pragma unroll
    for (int p = 0; p < 6; ++p)
        out[row * 6 + p] = o[p];
}

// ---------------------------------------------------------------------------
extern "C" void kernel_launch(void* const* d_in, const int* in_sizes, int n_in,
                              void* d_out, int out_size, void* d_ws, size_t ws_size,
                              hipStream_t stream) {
    const float* X     = (const float*)d_in[0];
    const float* fw    = (const float*)d_in[1];
    const float* capW  = (const float*)d_in[2];
    const float* cap_b = (const float*)d_in[3];
    const float* qW    = (const float*)d_in[4];
    const float* qb    = (const float*)d_in[5];
    const float* kW    = (const float*)d_in[6];
    const float* kb    = (const float*)d_in[7];
    const float* vW    = (const float*)d_in[8];
    const float* vb    = (const float*)d_in[9];
    const float* fc1W  = (const float*)d_in[10];
    const float* fc1b  = (const float*)d_in[11];
    const float* fc2W  = (const float*)d_in[12];
    const float* fc2b  = (const float*)d_in[13];
    const float* resW  = (const float*)d_in[14];
    const float* resb  = (const float*)d_in[15];
    const float* outW  = (const float*)d_in[16];
    const float* outb  = (const float*)d_in[17];
    float* out = (float*)d_out;
    float* Wt  = (float*)d_ws;

    const int use_wt =
        (ws_size >= (size_t)(INPUT_DIM * NCD) * sizeof(float)) ? 1 : 0;
    if (use_wt) {
        prep_wt<<<(INPUT_DIM * NCD + 255) / 256, 256, 0, stream>>>(capW, fw, Wt);
    }

    const int nrows = in_sizes[0] / INPUT_DIM;   // 65536
    harcnet_main<<<nrows / 64, 256, 0, stream>>>(
        X, fw, capW, cap_b, qW, qb, kW, kb, vW, vb,
        fc1W, fc1b, fc2W, fc2b, resW, resb, outW, outb,
        Wt, use_wt, out);
}

// Round 9
// 382.741 us; speedup vs baseline: 1.4890x; 1.2970x over previous
//
#include <hip/hip_runtime.h>
#include <math.h>

#define INPUT_DIM 561
#define NCD 32   // NUM_CAPS * CAP_DIM

// ---------------------------------------------------------------------------
// Prep: Wt[k][c] = cap_W[c][k] * fw[k]  (fold feature_weights; [561][32]
// layout so per-k weight rows are contiguous -> batched uniform s_loads)
// ---------------------------------------------------------------------------
__global__ void prep_wt(const float* __restrict__ capW,
                        const float* __restrict__ fw,
                        float* __restrict__ Wt) {
    int idx = blockIdx.x * blockDim.x + threadIdx.x;
    if (idx < INPUT_DIM * NCD) {
        int k = idx >> 5;       // 0..560
        int c = idx & 31;       // 0..31
        Wt[idx] = capW[c * INPUT_DIM + k] * fw[k];
    }
}

// ---------------------------------------------------------------------------
// Coalesced async staging (HW-verified pattern from round 4): wave w_s DMAs
// rows [16w,16w+16) of the block's 64-row tile; one instruction per row =
// 64 lanes x 4B contiguous into dst[p][0..63]. Pad (65) sits between rows.
// ---------------------------------------------------------------------------
__device__ __forceinline__ void stage16(const float* __restrict__ X,
                                        int r0, int k0, int w_s, int lane,
                                        float (*dst)[65]) {
    int kk = k0 + lane;
    if (kk > INPUT_DIM - 1) kk = INPUT_DIM - 1;   // clamp tail cols (unused)
    #pragma unroll
    for (int i = 0; i < 16; ++i) {
        const int p = w_s * 16 + i;
        const float* g = X + (size_t)(r0 + p) * INPUT_DIM + kk;
        __builtin_amdgcn_global_load_lds(
            (const __attribute__((address_space(1))) void*)g,
            (__attribute__((address_space(3))) void*)&dst[p][0],
            4, 0, 0);
    }
}

// ---------------------------------------------------------------------------
// Kernel A: caps GEMM. 256 thr = 4 waves; 64 rows/block; waves K-split each
// 64-col chunk 16 cols apiece. Register budget pinned to exactly 4 waves/EU
// (128 VGPRs) — round-6 post-mortem: without the pin the allocator shrank
// to 64 VGPRs and spilled the hot loop (170 MB scratch writes observed).
// ---------------------------------------------------------------------------
__global__ void __launch_bounds__(256)
__attribute__((amdgpu_waves_per_eu(4, 4)))
caps_gemm(const float* __restrict__ X,
          const float* __restrict__ Wt,
          const float* __restrict__ cap_b,
          float* __restrict__ caps)
{
    // union: staging dbuf [2][64][65]=8320 f  <->  partials [4][64][33]=8448 f
    __shared__ float smem[8448];                    // 33792 B -> 4 blocks/CU
    float (*xb)[64][65]   = (float (*)[64][65])smem;
    float (*part)[64][33] = (float (*)[64][33])smem;

    const int tid = threadIdx.x;
    const int t   = tid & 63;                       // row within block
    const int w   = tid >> 6;                       // wave id
    const int w_s = __builtin_amdgcn_readfirstlane(w);  // provably uniform
    const int r0  = blockIdx.x * 64;

    float acc[NCD];
    #pragma unroll
    for (int c = 0; c < NCD; ++c) acc[c] = 0.0f;

    // prologue: stage chunk 0
    stage16(X, r0, 0, w_s, t, xb[0]);

    // tail-chunk (49 cols) split 13/12/12/12
    const int tb = (w_s == 0) ? 0 : (13 + 12 * (w_s - 1));
    const int te = tb + ((w_s == 0) ? 13 : 12);

    int cur = 0;
    for (int ch = 0; ch < 9; ++ch) {
        asm volatile("s_waitcnt vmcnt(0)" ::: "memory");  // own DMA landed
        __syncthreads();                                  // everyone's landed
        const int k0 = ch * 64;
        if (ch < 8) stage16(X, r0, k0 + 64, w_s, t, xb[cur ^ 1]);

        if (ch < 8) {
            const int kb = w_s * 16;
            #pragma unroll 4
            for (int jj = 0; jj < 16; ++jj) {
                const int j = kb + jj;
                const float xv = xb[cur][t][j];           // (t+j)%32: 2-way free
                const float* __restrict__ wrow = Wt + (size_t)(k0 + j) * NCD;
                #pragma unroll
                for (int c = 0; c < NCD; ++c)
                    acc[c] = fmaf(xv, wrow[c], acc[c]);   // uniform -> s_load
            }
        } else {
            for (int j = tb; j < te; ++j) {
                const float xv = xb[cur][t][j];
                const float* __restrict__ wrow = Wt + (size_t)(k0 + j) * NCD;
                #pragma unroll
                for (int c = 0; c < NCD; ++c)
                    acc[c] = fmaf(xv, wrow[c], acc[c]);
            }
        }
        cur ^= 1;
    }

    __syncthreads();                   // done reading xb -> reuse smem
    #pragma unroll
    for (int c = 0; c < NCD; ++c) part[w][t][c] = acc[c];  // (t+c)%32 2-way
    __syncthreads();
    if (w != 0) return;

    // 8x float4 stores: guarantee dwordx4 codegen for the 8 MB intermediate
    float4* __restrict__ crow = (float4*)(caps + (size_t)(r0 + t) * NCD);
    #pragma unroll
    for (int v = 0; v < 8; ++v) {
        float4 s;
        s.x = cap_b[4*v+0] + part[0][t][4*v+0] + part[1][t][4*v+0]
            + part[2][t][4*v+0] + part[3][t][4*v+0];
        s.y = cap_b[4*v+1] + part[0][t][4*v+1] + part[1][t][4*v+1]
            + part[2][t][4*v+1] + part[3][t][4*v+1];
        s.z = cap_b[4*v+2] + part[0][t][4*v+2] + part[1][t][4*v+2]
            + part[2][t][4*v+2] + part[3][t][4*v+2];
        s.w = cap_b[4*v+3] + part[0][t][4*v+3] + part[1][t][4*v+3]
            + part[2][t][4*v+3] + part[3][t][4*v+3];
        crow[v] = s;
    }
}

// ---------------------------------------------------------------------------
// Head body (shared by split-head kernel and fused fallback).
// ---------------------------------------------------------------------------
__device__ __forceinline__ void head_body(
    const float* __restrict__ acc,
    const float* __restrict__ qW, const float* __restrict__ qb,
    const float* __restrict__ kW, const float* __restrict__ kb,
    const float* __restrict__ vW, const float* __restrict__ vb,
    const float* __restrict__ fc1W, const float* __restrict__ fc1b,
    const float* __restrict__ fc2W, const float* __restrict__ fc2b,
    const float* __restrict__ resW, const float* __restrict__ resb,
    const float* __restrict__ outW, const float* __restrict__ outb,
    float* __restrict__ o)
{
    float Km[32], Vm[32];
    #pragma unroll
    for (int q = 0; q < 4; ++q) {
        #pragma unroll
        for (int d = 0; d < 8; ++d) {
            float ka = kb[d], va = vb[d];
            #pragma unroll
            for (int e = 0; e < 8; ++e) {
                ka = fmaf(acc[q * 8 + e], kW[d * 8 + e], ka);
                va = fmaf(acc[q * 8 + e], vW[d * 8 + e], va);
            }
            Km[q * 8 + d] = ka;
            Vm[q * 8 + d] = va;
        }
    }

    float flat[32];
    const float rs8 = 0.35355339059327373f;  // 1/sqrt(8)
    #pragma unroll
    for (int q = 0; q < 4; ++q) {
        float Q[8];
        #pragma unroll
        for (int d = 0; d < 8; ++d) {
            float a = qb[d];
            #pragma unroll
            for (int e = 0; e < 8; ++e)
                a = fmaf(acc[q * 8 + e], qW[d * 8 + e], a);
            Q[d] = a;
        }
        float sc[4];
        #pragma unroll
        for (int kq = 0; kq < 4; ++kq) {
            float a = 0.0f;
            #pragma unroll
            for (int d = 0; d < 8; ++d)
                a = fmaf(Q[d], Km[kq * 8 + d], a);
            sc[kq] = a * rs8;
        }
        const float m  = fmaxf(fmaxf(sc[0], sc[1]), fmaxf(sc[2], sc[3]));
        const float e0 = __expf(sc[0] - m);
        const float e1 = __expf(sc[1] - m);
        const float e2 = __expf(sc[2] - m);
        const float e3 = __expf(sc[3] - m);
        const float inv = 1.0f / (e0 + e1 + e2 + e3);
        #pragma unroll
        for (int d = 0; d < 8; ++d)
            flat[q * 8 + d] =
                (e0 * Vm[0 * 8 + d] + e1 * Vm[1 * 8 + d] +
                 e2 * Vm[2 * 8 + d] + e3 * Vm[3 * 8 + d]) * inv;
    }

    float res[64];
    #pragma unroll
    for (int j = 0; j < 64; ++j) {
        float a = fc1b[j];
        #pragma unroll
        for (int i = 0; i < 32; ++i)
            a = fmaf(flat[i], fc1W[j * 32 + i], a);
        res[j] = fmaxf(a, 0.0f);
    }

    #pragma unroll
    for (int p = 0; p < 6; ++p) o[p] = outb[p];
    for (int c = 0; c < 64; ++c) {
        float a = fc2b[c] + resb[c];
        #pragma unroll
        for (int j = 0; j < 64; ++j)
            a = fmaf(res[j], fc2W[c * 64 + j], a);
        #pragma unroll
        for (int i = 0; i < 32; ++i)
            a = fmaf(flat[i], resW[c * 32 + i], a);
        a = fmaxf(a, 0.0f);
        #pragma unroll
        for (int p = 0; p < 6; ++p)
            o[p] = fmaf(a, outW[p * 64 + c], o[p]);
    }
}

// ---------------------------------------------------------------------------
// Kernel B: head. 1 thread/row. waves_per_eu(1,1): full register budget so
// res[64]/flat/Km/Vm never spill (round-6 lesson). 1024 waves = 4/CU, all
// resident; pure compute, weight reads are uniform (scalar pipe) + L2-hit.
// ---------------------------------------------------------------------------
__global__ void __launch_bounds__(256)
__attribute__((amdgpu_waves_per_eu(1, 1)))
head_kernel(const float* __restrict__ caps,
            const float* __restrict__ qW, const float* __restrict__ qb,
            const float* __restrict__ kW, const float* __restrict__ kb,
            const float* __restrict__ vW, const float* __restrict__ vb,
            const float* __restrict__ fc1W, const float* __restrict__ fc1b,
            const float* __restrict__ fc2W, const float* __restrict__ fc2b,
            const float* __restrict__ resW, const float* __restrict__ resb,
            const float* __restrict__ outW, const float* __restrict__ outb,
            float* __restrict__ out)
{
    const int row = blockIdx.x * 256 + threadIdx.x;
    // caps row is 128B-aligned & contiguous -> 8x float4 loads
    const float4* __restrict__ cp = (const float4*)(caps + (size_t)row * NCD);
    float acc[NCD];
    #pragma unroll
    for (int i = 0; i < 8; ++i) {
        const float4 v = cp[i];
        acc[4 * i + 0] = v.x; acc[4 * i + 1] = v.y;
        acc[4 * i + 2] = v.z; acc[4 * i + 3] = v.w;
    }
    float o[6];
    head_body(acc, qW, qb, kW, kb, vW, vb, fc1W, fc1b, fc2W, fc2b,
              resW, resb, outW, outb, o);
    #pragma unroll
    for (int p = 0; p < 6; ++p) out[row * 6 + p] = o[p];
}

// ---------------------------------------------------------------------------
// Fused fallback (only if ws too small for the caps buffer; not expected).
// ---------------------------------------------------------------------------
__global__ void __launch_bounds__(256)
harcnet_fused(const float* __restrict__ X,
              const float* __restrict__ fw,
              const float* __restrict__ capW, const float* __restrict__ cap_b,
              const float* __restrict__ qW, const float* __restrict__ qb,
              const float* __restrict__ kW, const float* __restrict__ kb,
              const float* __restrict__ vW, const float* __restrict__ vb,
              const float* __restrict__ fc1W, const float* __restrict__ fc1b,
              const float* __restrict__ fc2W, const float* __restrict__ fc2b,
              const float* __restrict__ resW, const float* __restrict__ resb,
              const float* __restrict__ outW, const float* __restrict__ outb,
              float* __restrict__ out)
{
    __shared__ float part[4][64][33];
    const int t   = threadIdx.x & 63;
    const int w   = threadIdx.x >> 6;
    const int row = blockIdx.x * 64 + t;
    const float* __restrict__ Xrow = X + (size_t)row * INPUT_DIM;

    float acc[NCD];
    #pragma unroll
    for (int c = 0; c < NCD; ++c) acc[c] = 0.0f;

    const int kbeg = w * 141;
    const int kend = (kbeg + 141 < INPUT_DIM) ? kbeg + 141 : INPUT_DIM;
    for (int k = kbeg; k < kend; ++k) {
        const float xv = Xrow[k] * fw[k];
        #pragma unroll
        for (int c = 0; c < NCD; ++c)
            acc[c] = fmaf(xv, capW[c * INPUT_DIM + k], acc[c]);
    }

    #pragma unroll
    for (int c = 0; c < NCD; ++c) part[w][t][c] = acc[c];
    __syncthreads();
    if (w != 0) return;
    #pragma unroll
    for (int c = 0; c < NCD; ++c)
        acc[c] = cap_b[c] + part[0][t][c] + part[1][t][c]
                          + part[2][t][c] + part[3][t][c];
    float o[6];
    head_body(acc, qW, qb, kW, kb, vW, vb, fc1W, fc1b, fc2W, fc2b,
              resW, resb, outW, outb, o);
    #pragma unroll
    for (int p = 0; p < 6; ++p) out[row * 6 + p] = o[p];
}

// ---------------------------------------------------------------------------
extern "C" void kernel_launch(void* const* d_in, const int* in_sizes, int n_in,
                              void* d_out, int out_size, void* d_ws, size_t ws_size,
                              hipStream_t stream) {
    const float* X     = (const float*)d_in[0];
    const float* fw    = (const float*)d_in[1];
    const float* capW  = (const float*)d_in[2];
    const float* cap_b = (const float*)d_in[3];
    const float* qW    = (const float*)d_in[4];
    const float* qb    = (const float*)d_in[5];
    const float* kW    = (const float*)d_in[6];
    const float* kb    = (const float*)d_in[7];
    const float* vW    = (const float*)d_in[8];
    const float* vb    = (const float*)d_in[9];
    const float* fc1W  = (const float*)d_in[10];
    const float* fc1b  = (const float*)d_in[11];
    const float* fc2W  = (const float*)d_in[12];
    const float* fc2b  = (const float*)d_in[13];
    const float* resW  = (const float*)d_in[14];
    const float* resb  = (const float*)d_in[15];
    const float* outW  = (const float*)d_in[16];
    const float* outb  = (const float*)d_in[17];
    float* out = (float*)d_out;

    const int nrows = in_sizes[0] / INPUT_DIM;   // 65536
    const size_t caps_off   = 73728;             // 128B-aligned, past Wt (71808)
    const size_t caps_bytes = (size_t)nrows * NCD * sizeof(float);     // 8 MB

    float* Wt   = (float*)d_ws;
    float* caps = (float*)((char*)d_ws + caps_off);

    if (ws_size >= caps_off + caps_bytes) {
        prep_wt<<<(INPUT_DIM * NCD + 255) / 256, 256, 0, stream>>>(capW, fw, Wt);
        caps_gemm<<<nrows / 64, 256, 0, stream>>>(X, Wt, cap_b, caps);
        head_kernel<<<nrows / 256, 256, 0, stream>>>(
            caps, qW, qb, kW, kb, vW, vb, fc1W, fc1b, fc2W, fc2b,
            resW, resb, outW, outb, out);
    } else {
        harcnet_fused<<<nrows / 64, 256, 0, stream>>>(
            X, fw, capW, cap_b, qW, qb, kW, kb, vW, vb,
            fc1W, fc1b, fc2W, fc2b, resW, resb, outW, outb, out);
    }
}

// Round 11
// 332.648 us; speedup vs baseline: 1.7132x; 1.1506x over previous
//
#include <hip/hip_runtime.h>
#include <math.h>

#define INPUT_DIM 561
#define NCD 32   // NUM_CAPS * CAP_DIM

// packed head-weight blob offsets (floats)
#define QW   0
#define QB   64
#define KW   72
#define KB   136
#define VW   144
#define VB   208
#define FC1W 216
#define FC1B 2264
#define FC2W 2328
#define FC2B 6424
#define RESW 6488
#define RESB 8536
#define OUTW 8600
#define OUTB 8984
#define HW_N 8990

// ---------------------------------------------------------------------------
// Prep 1: Wt[k][c] = cap_W[c][k] * fw[k]  (fold feature_weights; [561][32])
// ---------------------------------------------------------------------------
__global__ void prep_wt(const float* __restrict__ capW,
                        const float* __restrict__ fw,
                        float* __restrict__ Wt) {
    int idx = blockIdx.x * blockDim.x + threadIdx.x;
    if (idx < INPUT_DIM * NCD) {
        int k = idx >> 5;
        int c = idx & 31;
        Wt[idx] = capW[c * INPUT_DIM + k] * fw[k];
    }
}

// ---------------------------------------------------------------------------
// Prep 2: pack all head weights into one contiguous blob (so the head kernel
// can stage them to LDS with a single coalesced loop).
// ---------------------------------------------------------------------------
__global__ void pack_hw(const float* __restrict__ qW, const float* __restrict__ qb,
                        const float* __restrict__ kW, const float* __restrict__ kb,
                        const float* __restrict__ vW, const float* __restrict__ vb,
                        const float* __restrict__ fc1W, const float* __restrict__ fc1b,
                        const float* __restrict__ fc2W, const float* __restrict__ fc2b,
                        const float* __restrict__ resW, const float* __restrict__ resb,
                        const float* __restrict__ outW, const float* __restrict__ outb,
                        float* __restrict__ hw) {
    int i = blockIdx.x * blockDim.x + threadIdx.x;
    if (i >= HW_N) return;
    float v;
    if      (i < QB)   v = qW[i - QW];
    else if (i < KW)   v = qb[i - QB];
    else if (i < KB)   v = kW[i - KW];
    else if (i < VW)   v = kb[i - KB];
    else if (i < VB)   v = vW[i - VW];
    else if (i < FC1W) v = vb[i - VB];
    else if (i < FC1B) v = fc1W[i - FC1W];
    else if (i < FC2W) v = fc1b[i - FC1B];
    else if (i < FC2B) v = fc2W[i - FC2W];
    else if (i < RESW) v = fc2b[i - FC2B];
    else if (i < RESB) v = resW[i - RESW];
    else if (i < OUTW) v = resb[i - RESB];
    else if (i < OUTB) v = outW[i - OUTW];
    else               v = outb[i - OUTB];
    hw[i] = v;
}

// ---------------------------------------------------------------------------
// Coalesced async staging (HW-verified): wave w_s DMAs rows [16w,16w+16);
// one instruction per row = 64 lanes x 4B contiguous into dst[p][0..63].
// ---------------------------------------------------------------------------
__device__ __forceinline__ void stage16(const float* __restrict__ X,
                                        int r0, int k0, int w_s, int lane,
                                        float (*dst)[65]) {
    int kk = k0 + lane;
    if (kk > INPUT_DIM - 1) kk = INPUT_DIM - 1;
    #pragma unroll
    for (int i = 0; i < 16; ++i) {
        const int p = w_s * 16 + i;
        const float* g = X + (size_t)(r0 + p) * INPUT_DIM + kk;
        __builtin_amdgcn_global_load_lds(
            (const __attribute__((address_space(1))) void*)g,
            (__attribute__((address_space(3))) void*)&dst[p][0],
            4, 0, 0);
    }
}

// ---------------------------------------------------------------------------
// Kernel A: caps GEMM. 4 waves x 64 rows/block, 16-col K-split per wave.
// Batch the 16 xv LDS reads into regs first (one lgkmcnt drain), then a
// fully-unrolled s_load-weight FMA loop (decoupled counters). Register
// budget pinned to 4 waves/EU (R6: unpinned -> 64 VGPRs + 170 MB spill).
// ---------------------------------------------------------------------------
__global__ void __launch_bounds__(256)
__attribute__((amdgpu_waves_per_eu(4, 4)))
caps_gemm(const float* __restrict__ X,
          const float* __restrict__ Wt,
          const float* __restrict__ cap_b,
          float* __restrict__ caps)
{
    __shared__ float smem[8448];                    // 33792 B -> 4 blocks/CU
    float (*xb)[64][65]   = (float (*)[64][65])smem;
    float (*part)[64][33] = (float (*)[64][33])smem;

    const int tid = threadIdx.x;
    const int t   = tid & 63;
    const int w   = tid >> 6;
    const int w_s = __builtin_amdgcn_readfirstlane(w);
    const int r0  = blockIdx.x * 64;

    float acc[NCD];
    #pragma unroll
    for (int c = 0; c < NCD; ++c) acc[c] = 0.0f;

    stage16(X, r0, 0, w_s, t, xb[0]);

    const int tb = (w_s == 0) ? 0 : (13 + 12 * (w_s - 1));
    const int te = tb + ((w_s == 0) ? 13 : 12);

    int cur = 0;
    for (int ch = 0; ch < 9; ++ch) {
        asm volatile("s_waitcnt vmcnt(0)" ::: "memory");
        __syncthreads();
        const int k0 = ch * 64;
        if (ch < 8) stage16(X, r0, k0 + 64, w_s, t, xb[cur ^ 1]);

        if (ch < 8) {
            const int kb = w_s * 16;
            float xv[16];
            #pragma unroll
            for (int jj = 0; jj < 16; ++jj)      // (t+kb+jj)%32: 2-way = free
                xv[jj] = xb[cur][t][kb + jj];
            #pragma unroll
            for (int jj = 0; jj < 16; ++jj) {
                const float* __restrict__ wrow = Wt + (size_t)(k0 + kb + jj) * NCD;
                #pragma unroll
                for (int c = 0; c < NCD; ++c)
                    acc[c] = fmaf(xv[jj], wrow[c], acc[c]);   // uniform s_load
            }
        } else {
            for (int j = tb; j < te; ++j) {
                const float xv = xb[cur][t][j];
                const float* __restrict__ wrow = Wt + (size_t)(k0 + j) * NCD;
                #pragma unroll
                for (int c = 0; c < NCD; ++c)
                    acc[c] = fmaf(xv, wrow[c], acc[c]);
            }
        }
        cur ^= 1;
    }

    __syncthreads();
    #pragma unroll
    for (int c = 0; c < NCD; ++c) part[w][t][c] = acc[c];
    __syncthreads();
    if (w != 0) return;

    float4* __restrict__ crow = (float4*)(caps + (size_t)(r0 + t) * NCD);
    #pragma unroll
    for (int v = 0; v < 8; ++v) {
        float4 s;
        s.x = cap_b[4*v+0] + part[0][t][4*v+0] + part[1][t][4*v+0]
            + part[2][t][4*v+0] + part[3][t][4*v+0];
        s.y = cap_b[4*v+1] + part[0][t][4*v+1] + part[1][t][4*v+1]
            + part[2][t][4*v+1] + part[3][t][4*v+1];
        s.z = cap_b[4*v+2] + part[0][t][4*v+2] + part[1][t][4*v+2]
            + part[2][t][4*v+2] + part[3][t][4*v+2];
        s.w = cap_b[4*v+3] + part[0][t][4*v+3] + part[1][t][4*v+3]
            + part[2][t][4*v+3] + part[3][t][4*v+3];
        crow[v] = s;
    }
}

// ---------------------------------------------------------------------------
// Kernel B: head v2. 4 threads per row (hidden dim split 16-apiece) ->
// 1024 blocks x 4 waves = 16 waves/CU (R9: 128 us at 1 wave/SIMD was
// grid-limited latency exposure). All weights read from LDS (broadcast).
// ---------------------------------------------------------------------------
__global__ void __launch_bounds__(256)
__attribute__((amdgpu_waves_per_eu(3, 4)))
head_kernel(const float* __restrict__ caps,
            const float* __restrict__ hwg,
            float* __restrict__ out)
{
    __shared__ float hw[HW_N];
    const int tid = threadIdx.x;
    for (int i = tid; i < HW_N; i += 256) hw[i] = hwg[i];   // coalesced fill
    __syncthreads();

    const int g    = tid & 3;            // hidden-split id
    const int row  = blockIdx.x * 64 + (tid >> 2);
    const int lane = tid & 63;

    // ---- attention (redundant across the 4 group threads; ~1.3k FMA) ----
    const float4* __restrict__ cp = (const float4*)(caps + (size_t)row * NCD);
    float acc[NCD];
    #pragma unroll
    for (int i = 0; i < 8; ++i) {
        const float4 v = cp[i];
        acc[4*i+0] = v.x; acc[4*i+1] = v.y; acc[4*i+2] = v.z; acc[4*i+3] = v.w;
    }

    float Km[32], Vm[32];
    #pragma unroll
    for (int q = 0; q < 4; ++q) {
        #pragma unroll
        for (int d = 0; d < 8; ++d) {
            float ka = hw[KB + d], va = hw[VB + d];
            #pragma unroll
            for (int e = 0; e < 8; ++e) {
                ka = fmaf(acc[q*8+e], hw[KW + d*8+e], ka);
                va = fmaf(acc[q*8+e], hw[VW + d*8+e], va);
            }
            Km[q*8+d] = ka;
            Vm[q*8+d] = va;
        }
    }

    float flat[32];
    const float rs8 = 0.35355339059327373f;
    #pragma unroll
    for (int q = 0; q < 4; ++q) {
        float Q[8];
        #pragma unroll
        for (int d = 0; d < 8; ++d) {
            float a = hw[QB + d];
            #pragma unroll
            for (int e = 0; e < 8; ++e)
                a = fmaf(acc[q*8+e], hw[QW + d*8+e], a);
            Q[d] = a;
        }
        float sc[4];
        #pragma unroll
        for (int kq = 0; kq < 4; ++kq) {
            float a = 0.0f;
            #pragma unroll
            for (int d = 0; d < 8; ++d)
                a = fmaf(Q[d], Km[kq*8+d], a);
            sc[kq] = a * rs8;
        }
        const float m  = fmaxf(fmaxf(sc[0], sc[1]), fmaxf(sc[2], sc[3]));
        const float e0 = __expf(sc[0]-m), e1 = __expf(sc[1]-m);
        const float e2 = __expf(sc[2]-m), e3 = __expf(sc[3]-m);
        const float inv = 1.0f / (e0+e1+e2+e3);
        #pragma unroll
        for (int d = 0; d < 8; ++d)
            flat[q*8+d] = (e0*Vm[0*8+d] + e1*Vm[1*8+d] +
                           e2*Vm[2*8+d] + e3*Vm[3*8+d]) * inv;
    }

    // ---- fc1: my 16 hidden units j = g*16 + jj ----
    const int j0 = g * 16;
    float res_[16];
    #pragma unroll
    for (int jj = 0; jj < 16; ++jj) {
        const int j = j0 + jj;
        float a = hw[FC1B + j];
        #pragma unroll
        for (int i = 0; i < 32; ++i)
            a = fmaf(flat[i], hw[FC1W + j*32 + i], a);
        res_[jj] = fmaxf(a, 0.0f);
    }

    // ---- gather full res[64] from the 4 group lanes (static idx only) ----
    float res_full[64];
    const int lbase = lane & ~3;
    #pragma unroll
    for (int gg = 0; gg < 4; ++gg) {
        #pragma unroll
        for (int jj = 0; jj < 16; ++jj)
            res_full[gg*16 + jj] = __shfl(res_[jj], lbase | gg, 64);
    }

    // ---- fc2 + residual + relu + out-proj for my 16 c ----
    float o[6];
    #pragma unroll
    for (int p = 0; p < 6; ++p) o[p] = 0.0f;

    #pragma unroll 2
    for (int cc = 0; cc < 16; ++cc) {
        const int c = j0 + cc;
        float s = hw[FC2B + c] + hw[RESB + c];
        #pragma unroll
        for (int j = 0; j < 64; ++j)
            s = fmaf(res_full[j], hw[FC2W + c*64 + j], s);
        #pragma unroll
        for (int i = 0; i < 32; ++i)
            s = fmaf(flat[i], hw[RESW + c*32 + i], s);
        s = fmaxf(s, 0.0f);
        #pragma unroll
        for (int p = 0; p < 6; ++p)
            o[p] = fmaf(s, hw[OUTW + p*64 + c], o[p]);
    }

    // ---- reduce over the 4 group lanes, writer adds bias ----
    #pragma unroll
    for (int p = 0; p < 6; ++p) {
        o[p] += __shfl_xor(o[p], 1, 64);
        o[p] += __shfl_xor(o[p], 2, 64);
    }
    if (g == 0) {
        #pragma unroll
        for (int p = 0; p < 6; ++p)
            out[row*6 + p] = o[p] + hw[OUTB + p];
    }
}

// ---------------------------------------------------------------------------
// Fused fallback (only if ws too small; slow but correct).
// ---------------------------------------------------------------------------
__global__ void __launch_bounds__(256)
harcnet_fused(const float* __restrict__ X,
              const float* __restrict__ fw,
              const float* __restrict__ capW, const float* __restrict__ cap_b,
              const float* __restrict__ qW, const float* __restrict__ qb,
              const float* __restrict__ kW, const float* __restrict__ kb,
              const float* __restrict__ vW, const float* __restrict__ vb,
              const float* __restrict__ fc1W, const float* __restrict__ fc1b,
              const float* __restrict__ fc2W, const float* __restrict__ fc2b,
              const float* __restrict__ resW, const float* __restrict__ resb,
              const float* __restrict__ outW, const float* __restrict__ outb,
              float* __restrict__ out)
{
    __shared__ float part[4][64][33];
    const int t   = threadIdx.x & 63;
    const int w   = threadIdx.x >> 6;
    const int row = blockIdx.x * 64 + t;
    const float* __restrict__ Xrow = X + (size_t)row * INPUT_DIM;

    float acc[NCD];
    #pragma unroll
    for (int c = 0; c < NCD; ++c) acc[c] = 0.0f;

    const int kbeg = w * 141;
    const int kend = (kbeg + 141 < INPUT_DIM) ? kbeg + 141 : INPUT_DIM;
    for (int k = kbeg; k < kend; ++k) {
        const float xv = Xrow[k] * fw[k];
        #pragma unroll
        for (int c = 0; c < NCD; ++c)
            acc[c] = fmaf(xv, capW[c * INPUT_DIM + k], acc[c]);
    }

    #pragma unroll
    for (int c = 0; c < NCD; ++c) part[w][t][c] = acc[c];
    __syncthreads();
    if (w != 0) return;
    #pragma unroll
    for (int c = 0; c < NCD; ++c)
        acc[c] = cap_b[c] + part[0][t][c] + part[1][t][c]
                          + part[2][t][c] + part[3][t][c];

    float Km[32], Vm[32];
    #pragma unroll
    for (int q = 0; q < 4; ++q)
        #pragma unroll
        for (int d = 0; d < 8; ++d) {
            float ka = kb[d], va = vb[d];
            #pragma unroll
            for (int e = 0; e < 8; ++e) {
                ka = fmaf(acc[q*8+e], kW[d*8+e], ka);
                va = fmaf(acc[q*8+e], vW[d*8+e], va);
            }
            Km[q*8+d] = ka; Vm[q*8+d] = va;
        }
    float flat[32];
    const float rs8 = 0.35355339059327373f;
    #pragma unroll
    for (int q = 0; q < 4; ++q) {
        float Q[8];
        #pragma unroll
        for (int d = 0; d < 8; ++d) {
            float a = qb[d];
            #pragma unroll
            for (int e = 0; e < 8; ++e) a = fmaf(acc[q*8+e], qW[d*8+e], a);
            Q[d] = a;
        }
        float sc[4];
        #pragma unroll
        for (int kq = 0; kq < 4; ++kq) {
            float a = 0.0f;
            #pragma unroll
            for (int d = 0; d < 8; ++d) a = fmaf(Q[d], Km[kq*8+d], a);
            sc[kq] = a * rs8;
        }
        const float m  = fmaxf(fmaxf(sc[0], sc[1]), fmaxf(sc[2], sc[3]));
        const float e0 = __expf(sc[0]-m), e1 = __expf(sc[1]-m);
        const float e2 = __expf(sc[2]-m), e3 = __expf(sc[3]-m);
        const float inv = 1.0f / (e0+e1+e2+e3);
        #pragma unroll
        for (int d = 0; d < 8; ++d)
            flat[q*8+d] = (e0*Vm[0*8+d]+e1*Vm[1*8+d]+e2*Vm[2*8+d]+e3*Vm[3*8+d])*inv;
    }
    float res[64];
    #pragma unroll
    for (int j = 0; j < 64; ++j) {
        float a = fc1b[j];
        #pragma unroll
        for (int i = 0; i < 32; ++i) a = fmaf(flat[i], fc1W[j*32+i], a);
        res[j] = fmaxf(a, 0.0f);
    }
    float o[6];
    #pragma unroll
    for (int p = 0; p < 6; ++p) o[p] = outb[p];
    for (int c = 0; c < 64; ++c) {
        float a = fc2b[c] + resb[c];
        #pragma unroll
        for (int j = 0; j < 64; ++j) a = fmaf(res[j], fc2W[c*64+j], a);
        #pragma unroll
        for (int i = 0; i < 32; ++i) a = fmaf(flat[i], resW[c*32+i], a);
        a = fmaxf(a, 0.0f);
        #pragma unroll
        for (int p = 0; p < 6; ++p) o[p] = fmaf(a, outW[p*64+c], o[p]);
    }
    #pragma unroll
    for (int p = 0; p < 6; ++p) out[row*6+p] = o[p];
}

// ---------------------------------------------------------------------------
extern "C" void kernel_launch(void* const* d_in, const int* in_sizes, int n_in,
                              void* d_out, int out_size, void* d_ws, size_t ws_size,
                              hipStream_t stream) {
    const float* X     = (const float*)d_in[0];
    const float* fw    = (const float*)d_in[1];
    const float* capW  = (const float*)d_in[2];
    const float* cap_b = (const float*)d_in[3];
    const float* qW    = (const float*)d_in[4];
    const float* qb    = (const float*)d_in[5];
    const float* kW    = (const float*)d_in[6];
    const float* kb    = (const float*)d_in[7];
    const float* vW    = (const float*)d_in[8];
    const float* vb    = (const float*)d_in[9];
    const float* fc1W  = (const float*)d_in[10];
    const float* fc1b  = (const float*)d_in[11];
    const float* fc2W  = (const float*)d_in[12];
    const float* fc2b  = (const float*)d_in[13];
    const float* resW  = (const float*)d_in[14];
    const float* resb  = (const float*)d_in[15];
    const float* outW  = (const float*)d_in[16];
    const float* outb  = (const float*)d_in[17];
    float* out = (float*)d_out;

    const int nrows = in_sizes[0] / INPUT_DIM;   // 65536
    const size_t hw_off     = 73728;             // past Wt (71808), 128B align
    const size_t caps_off   = 110592;            // past hw (35960), 128B align
    const size_t caps_bytes = (size_t)nrows * NCD * sizeof(float);   // 8 MB

    float* Wt   = (float*)d_ws;
    float* hw   = (float*)((char*)d_ws + hw_off);
    float* caps = (float*)((char*)d_ws + caps_off);

    if (ws_size >= caps_off + caps_bytes) {
        prep_wt<<<(INPUT_DIM * NCD + 255) / 256, 256, 0, stream>>>(capW, fw, Wt);
        pack_hw<<<(HW_N + 255) / 256, 256, 0, stream>>>(
            qW, qb, kW, kb, vW, vb, fc1W, fc1b, fc2W, fc2b,
            resW, resb, outW, outb, hw);
        caps_gemm<<<nrows / 64, 256, 0, stream>>>(X, Wt, cap_b, caps);
        head_kernel<<<nrows / 64, 256, 0, stream>>>(caps, hw, out);
    } else {
        harcnet_fused<<<nrows / 64, 256, 0, stream>>>(
            X, fw, capW, cap_b, qW, qb, kW, kb, vW, vb,
            fc1W, fc1b, fc2W, fc2b, resW, resb, outW, outb, out);
    }
}